// Round 3
// baseline (13011.183 us; speedup 1.0000x reference)
//
#include <hip/hip_runtime.h>
#include <hip/hip_bf16.h>

#define T_STEPS 512
#define BATCH   64
#define IDIM    512
#define HDIM    1024
#define ODIM    512
#define NWG     256
#define TPB     256
#define JS      4             // hidden units per WG
#define KTOT    1536
#define NKT     48            // K-tiles of 32
#define ARRIVALS (NWG * 4)    // each wave arrives independently

typedef __bf16 bf16_t;
typedef bf16_t bf16x8 __attribute__((ext_vector_type(8)));
typedef float  f32x4  __attribute__((ext_vector_type(4)));
typedef unsigned short u16;
typedef unsigned int   u32;
typedef u16 u16x8 __attribute__((ext_vector_type(8)));

// ws layout (u32 units): [0,65536) h double buffer (2x64x1024 bf16);
// [65536,66560) 32 barrier counters spaced 128B; then X_bf16.
#define HBUF_U32 65536
#define CNT_U32  1024
#define XB_U16_OFF (2 * (HBUF_U32 + CNT_U32))

__device__ __forceinline__ float sigmoidf_fast(float x) {
  return 1.0f / (1.0f + __expf(-x));
}
__device__ __forceinline__ float tanhf_fast(float x) {
  float ax = fabsf(x);
  float e  = __expf(-2.0f * ax);
  return copysignf((1.0f - e) / (1.0f + e), x);
}

__global__ void k_init(u32* w) {
  int i = blockIdx.x * blockDim.x + threadIdx.x;
  for (int idx = i; idx < HBUF_U32 + CNT_U32; idx += gridDim.x * blockDim.x) w[idx] = 0u;
}

__global__ __launch_bounds__(TPB) void k_xcvt(const float* __restrict__ X,
                                              u16* __restrict__ Xb) {
  size_t i = ((size_t)blockIdx.x * TPB + threadIdx.x) * 8;
  f32x4 a = *(const f32x4*)(X + i);
  f32x4 b = *(const f32x4*)(X + i + 4);
  u16x8 o;
  o[0] = __builtin_bit_cast(u16, (bf16_t)a[0]);
  o[1] = __builtin_bit_cast(u16, (bf16_t)a[1]);
  o[2] = __builtin_bit_cast(u16, (bf16_t)a[2]);
  o[3] = __builtin_bit_cast(u16, (bf16_t)a[3]);
  o[4] = __builtin_bit_cast(u16, (bf16_t)b[0]);
  o[5] = __builtin_bit_cast(u16, (bf16_t)b[1]);
  o[6] = __builtin_bit_cast(u16, (bf16_t)b[2]);
  o[7] = __builtin_bit_cast(u16, (bf16_t)b[3]);
  *(u16x8*)(Xb + i) = o;
}

#define MF(ACC, A, KT) \
  ACC = __builtin_amdgcn_mfma_f32_16x16x32_bf16((A), wf[KT], (ACC), 0, 0, 0)

__global__ __launch_bounds__(TPB, 1) void k_lstm(
    const u16* __restrict__ Xb, const float* __restrict__ Wih,
    const float* __restrict__ Whh, const float* __restrict__ bih,
    const float* __restrict__ bhh, u16* __restrict__ hbuf,
    u32* __restrict__ cnt) {
  __shared__ float gw[4][16][17];   // per-wave gate exchange, +1 pad

  const int wg   = blockIdx.x;
  const int tid  = threadIdx.x;
  const int w    = tid >> 6;
  const int lane = tid & 63;
  const int am   = lane & 15;       // MFMA col / A-row-in-tile
  const int kg   = lane >> 4;       // k-group 0..3
  const int b    = 16 * w + am;     // batch row this lane supplies

  // col am -> gate row: col = gate*4 + j
  const int gate = am >> 2, j4 = am & 3;
  const int gr   = gate * HDIM + wg * JS + j4;
  const float bias = bih[gr] + bhh[gr];

  // ---- weights into registers: B-frag[kt] = W[col am][kt*32 + kg*8 .. +7] ----
  bf16x8 wf[NKT];
  #pragma unroll
  for (int kt = 0; kt < NKT; ++kt) {
    int k0 = kt * 32 + kg * 8;
    const float* src = (k0 < IDIM) ? (Wih + (size_t)gr * IDIM + k0)
                                   : (Whh + (size_t)gr * HDIM + (k0 - IDIM));
    f32x4 u = *(const f32x4*)src;
    f32x4 v = *(const f32x4*)(src + 4);
    bf16x8 tt;
    tt[0] = (bf16_t)u[0]; tt[1] = (bf16_t)u[1]; tt[2] = (bf16_t)u[2]; tt[3] = (bf16_t)u[3];
    tt[4] = (bf16_t)v[0]; tt[5] = (bf16_t)v[1]; tt[6] = (bf16_t)v[2]; tt[7] = (bf16_t)v[3];
    wf[kt] = tt;
  }

  // ---- X(0) prefetch ----
  bf16x8 xr[16];
  {
    const u16* xrow = Xb + (size_t)b * IDIM + kg * 8;
    #pragma unroll
    for (int kc = 0; kc < 16; ++kc) xr[kc] = *(const bf16x8*)(xrow + kc * 32);
  }

  // epilogue ownership: thread (w,kg,am) -> batch row 16w+kg*4+(am&3), hidden j = am>>2
  const int erow = kg * 4 + (am & 3);
  const int ejj  = am >> 2;
  float c = 0.f;

  int cur = 0;
  for (int t = 0; t < T_STEPS; ++t) {
    const u16* hrow = hbuf + (size_t)cur * BATCH * HDIM + (size_t)b * HDIM + kg * 8;
    bf16x8 hA[8], hB[8];
    #pragma unroll
    for (int q = 0; q < 8; ++q) hA[q] = *(const bf16x8*)(hrow + q * 32);

    f32x4 a0 = {bias, bias, bias, bias};
    f32x4 a1 = {0.f, 0.f, 0.f, 0.f};
    f32x4 a2 = {0.f, 0.f, 0.f, 0.f};
    f32x4 a3 = {0.f, 0.f, 0.f, 0.f};

    // X part: pure register MFMAs (covers h load latency)
    MF(a0, xr[0],  0); MF(a1, xr[1],  1); MF(a2, xr[2],  2); MF(a3, xr[3],  3);
    MF(a0, xr[4],  4); MF(a1, xr[5],  5); MF(a2, xr[6],  6); MF(a3, xr[7],  7);
    MF(a0, xr[8],  8); MF(a1, xr[9],  9); MF(a2, xr[10], 10); MF(a3, xr[11], 11);
    MF(a0, xr[12], 12); MF(a1, xr[13], 13); MF(a2, xr[14], 14); MF(a3, xr[15], 15);

    // X(t+1) prefetch (immutable; regs survive the cache invalidate)
    if (t != T_STEPS - 1) {
      const u16* xn = Xb + ((size_t)(t + 1) * BATCH + b) * IDIM + kg * 8;
      #pragma unroll
      for (int kc = 0; kc < 16; ++kc) xr[kc] = *(const bf16x8*)(xn + kc * 32);
    }

    // h part: 4 chunks of 8 k-tiles, register double-buffered
    #pragma unroll
    for (int q = 0; q < 8; ++q) hB[q] = *(const bf16x8*)(hrow + 256 + q * 32);
    MF(a0, hA[0], 16); MF(a1, hA[1], 17); MF(a2, hA[2], 18); MF(a3, hA[3], 19);
    MF(a0, hA[4], 20); MF(a1, hA[5], 21); MF(a2, hA[6], 22); MF(a3, hA[7], 23);

    #pragma unroll
    for (int q = 0; q < 8; ++q) hA[q] = *(const bf16x8*)(hrow + 512 + q * 32);
    MF(a0, hB[0], 24); MF(a1, hB[1], 25); MF(a2, hB[2], 26); MF(a3, hB[3], 27);
    MF(a0, hB[4], 28); MF(a1, hB[5], 29); MF(a2, hB[6], 30); MF(a3, hB[7], 31);

    #pragma unroll
    for (int q = 0; q < 8; ++q) hB[q] = *(const bf16x8*)(hrow + 768 + q * 32);
    MF(a0, hA[0], 32); MF(a1, hA[1], 33); MF(a2, hA[2], 34); MF(a3, hA[3], 35);
    MF(a0, hA[4], 36); MF(a1, hA[5], 37); MF(a2, hA[6], 38); MF(a3, hA[7], 39);

    MF(a0, hB[0], 40); MF(a1, hB[1], 41); MF(a2, hB[2], 42); MF(a3, hB[3], 43);
    MF(a0, hB[4], 44); MF(a1, hB[5], 45); MF(a2, hB[6], 46); MF(a3, hB[7], 47);

    f32x4 g = (a0 + a1) + (a2 + a3);

    // per-wave LDS exchange (no block barrier): D row = kg*4+i, col = am
    #pragma unroll
    for (int r = 0; r < 4; ++r) gw[w][kg * 4 + r][am] = g[r];
    asm volatile("s_waitcnt lgkmcnt(0)" ::: "memory");
    __builtin_amdgcn_sched_barrier(0);

    {
      float pi = gw[w][erow][ejj];
      float pf = gw[w][erow][4 + ejj];
      float pg = gw[w][erow][8 + ejj];
      float po = gw[w][erow][12 + ejj];
      c = sigmoidf_fast(pf) * c + sigmoidf_fast(pi) * tanhf_fast(pg);
      float h = sigmoidf_fast(po) * tanhf_fast(c);
      u16 hu = __builtin_bit_cast(u16, (bf16_t)h);
      u16* hp = hbuf + (size_t)(cur ^ 1) * BATCH * HDIM
              + (size_t)(16 * w + erow) * HDIM + wg * JS + ejj;
      // write-through to LLC: no wbl2 needed at the barrier
      asm volatile("global_store_short %0, %1, off sc0 sc1"
                   :: "v"(hp), "v"((u32)hu) : "memory");
    }

    if (t != T_STEPS - 1) {
      // per-wave arrival: own stores drained (write-through -> visible at LLC)
      asm volatile("s_waitcnt vmcnt(0)" ::: "memory");
      if (lane == 0)
        __hip_atomic_fetch_add(&cnt[((wg & 7) * 4 + w) * 32], 1u,
                               __ATOMIC_RELAXED, __HIP_MEMORY_SCOPE_AGENT);
      u32 target = (u32)(t + 1) * (u32)ARRIVALS;
      while (true) {
        u32 v = (lane < 32)
          ? __hip_atomic_load(&cnt[lane * 32], __ATOMIC_RELAXED, __HIP_MEMORY_SCOPE_AGENT)
          : 0u;
        v += __shfl_xor(v, 1);
        v += __shfl_xor(v, 2);
        v += __shfl_xor(v, 4);
        v += __shfl_xor(v, 8);
        v += __shfl_xor(v, 16);
        if (__shfl(v, 0) >= target) break;
        __builtin_amdgcn_s_sleep(1);
      }
      __builtin_amdgcn_fence(__ATOMIC_ACQUIRE, "agent");  // buffer_inv: drop stale L1/L2 h lines
    }
    cur ^= 1;
  }
}

__global__ __launch_bounds__(TPB) void k_out(
    const u16* __restrict__ hfin, const float* __restrict__ Who,
    const float* __restrict__ bho, float* __restrict__ out) {
  int gid = blockIdx.x * TPB + threadIdx.x;  // 0..32767
  int b   = gid & 63;
  int oc  = gid >> 6;
  const u16* hrow = hfin + b * HDIM;
  const float* wrow = Who + oc * HDIM;
  float s = bho[oc];
  for (int k = 0; k < HDIM; k += 8) {
    bf16x8 hv = *(const bf16x8*)(hrow + k);
    f32x4 w0 = *(const f32x4*)(wrow + k);
    f32x4 w1 = *(const f32x4*)(wrow + k + 4);
    s += (float)hv[0] * w0[0] + (float)hv[1] * w0[1] + (float)hv[2] * w0[2] + (float)hv[3] * w0[3]
       + (float)hv[4] * w1[0] + (float)hv[5] * w1[1] + (float)hv[6] * w1[2] + (float)hv[7] * w1[3];
  }
  out[b * ODIM + oc] = s;
}

extern "C" void kernel_launch(void* const* d_in, const int* in_sizes, int n_in,
                              void* d_out, int out_size, void* d_ws, size_t ws_size,
                              hipStream_t stream) {
  const float* X   = (const float*)d_in[0];
  const float* Wih = (const float*)d_in[1];
  const float* Whh = (const float*)d_in[2];
  const float* bih = (const float*)d_in[3];
  const float* bhh = (const float*)d_in[4];
  const float* Who = (const float*)d_in[5];
  const float* bho = (const float*)d_in[6];

  u32* ws32 = (u32*)d_ws;
  u16* hbuf = (u16*)d_ws;
  u32* cnt  = ws32 + HBUF_U32;
  u16* Xb   = (u16*)d_ws + XB_U16_OFF;

  k_init<<<64, TPB, 0, stream>>>(ws32);
  k_xcvt<<<(T_STEPS * BATCH * IDIM) / (TPB * 8), TPB, 0, stream>>>(X, Xb);
  k_lstm<<<NWG, TPB, 0, stream>>>(Xb, Wih, Whh, bih, bhh, hbuf, cnt);
  k_out<<<(BATCH * ODIM) / TPB, TPB, 0, stream>>>(hbuf, Who, bho, (float*)d_out);
}

// Round 4
// 4620.556 us; speedup vs baseline: 2.8159x; 2.8159x over previous
//
#include <hip/hip_runtime.h>
#include <hip/hip_bf16.h>

#define T_STEPS 512
#define BATCH   64
#define IDIM    512
#define HDIM    1024
#define ODIM    512
#define NWG     128
#define TPB     512           // 8 waves: split-K 8 ways
#define TPB2    256
#define JS      8             // hidden units per WG -> 32 gate cols

typedef __bf16 bf16_t;
typedef bf16_t bf16x8 __attribute__((ext_vector_type(8)));
typedef float  f32x4  __attribute__((ext_vector_type(4)));
typedef unsigned short u16;
typedef unsigned int   u32;
typedef u16 u16x8 __attribute__((ext_vector_type(8)));

// ws layout (u32 units): [0,65536) h double buffer (2x64x1024 bf16);
// [65536,66560) barrier counters (8 used, 128B apart); then X_bf16.
#define HBUF_U32 65536
#define CNT_U32  1024
#define XB_U16_OFF (2 * (HBUF_U32 + CNT_U32))

__device__ __forceinline__ float sigmoidf_fast(float x) {
  return 1.0f / (1.0f + __expf(-x));
}
__device__ __forceinline__ float tanhf_fast(float x) {
  float ax = fabsf(x);
  float e  = __expf(-2.0f * ax);
  return copysignf((1.0f - e) / (1.0f + e), x);
}

__global__ void k_init(u32* w) {
  int i = blockIdx.x * blockDim.x + threadIdx.x;
  for (int idx = i; idx < HBUF_U32 + CNT_U32; idx += gridDim.x * blockDim.x) w[idx] = 0u;
}

__global__ __launch_bounds__(TPB2) void k_xcvt(const float* __restrict__ X,
                                               u16* __restrict__ Xb) {
  size_t i = ((size_t)blockIdx.x * TPB2 + threadIdx.x) * 8;
  f32x4 a = *(const f32x4*)(X + i);
  f32x4 b = *(const f32x4*)(X + i + 4);
  u16x8 o;
  o[0] = __builtin_bit_cast(u16, (bf16_t)a[0]);
  o[1] = __builtin_bit_cast(u16, (bf16_t)a[1]);
  o[2] = __builtin_bit_cast(u16, (bf16_t)a[2]);
  o[3] = __builtin_bit_cast(u16, (bf16_t)a[3]);
  o[4] = __builtin_bit_cast(u16, (bf16_t)b[0]);
  o[5] = __builtin_bit_cast(u16, (bf16_t)b[1]);
  o[6] = __builtin_bit_cast(u16, (bf16_t)b[2]);
  o[7] = __builtin_bit_cast(u16, (bf16_t)b[3]);
  *(u16x8*)(Xb + i) = o;
}

__device__ __forceinline__ bf16x8 cvt8(const float* src) {
  f32x4 u = *(const f32x4*)src;
  f32x4 v = *(const f32x4*)(src + 4);
  bf16x8 t;
  t[0] = (bf16_t)u[0]; t[1] = (bf16_t)u[1]; t[2] = (bf16_t)u[2]; t[3] = (bf16_t)u[3];
  t[4] = (bf16_t)v[0]; t[5] = (bf16_t)v[1]; t[6] = (bf16_t)v[2]; t[7] = (bf16_t)v[3];
  return t;
}

// acc[ct][bt] += A * wf[i*2+ct]
#define MFA(CT, BT, AF, WI) \
  acc[CT][BT] = __builtin_amdgcn_mfma_f32_16x16x32_bf16((AF), wf[(WI)*2+(CT)], acc[CT][BT], 0, 0, 0)

__global__ __launch_bounds__(TPB, 2) void k_lstm(
    const u16* __restrict__ Xb, const float* __restrict__ Wih,
    const float* __restrict__ Whh, const float* __restrict__ bih,
    const float* __restrict__ bhh, u16* __restrict__ hbuf,
    u32* __restrict__ cnt) {
  // cross-wave partial-sum exchange: [wave][gate-col 32][batch 64 + pad 8]
  // stride 72: read bank=(8j+b)&31 (2-way, free); f32x4 writes row-contiguous
  __shared__ float gw[8][32][72];   // 73.7 KB

  const int wg   = blockIdx.x;
  const int tid  = threadIdx.x;
  const int w    = tid >> 6;        // wave 0..7 = k-split slice
  const int lane = tid & 63;
  const int am   = lane & 15;       // A-row / D-col within 16-tile
  const int kg   = lane >> 4;       // k-group 0..3

  // ---- time-invariant weights into registers: 12 frags = 48 VGPRs ----
  // wave w owns k-tiles kt = w + 8i (i=0..5); i=0,1 -> X (Wih), i=2..5 -> h (Whh)
  bf16x8 wf[12];
  {
    const int j8 = am & 7, gsel = am >> 3;
    #pragma unroll
    for (int ct = 0; ct < 2; ++ct) {
      int gr = (ct * 2 + gsel) * HDIM + wg * JS + j8;   // gate-col ct*16+am
      #pragma unroll
      for (int i = 0; i < 2; ++i) {
        int k0 = (w + 8 * i) * 32 + kg * 8;
        wf[i * 2 + ct] = cvt8(Wih + (size_t)gr * IDIM + k0);
      }
      #pragma unroll
      for (int i = 2; i < 6; ++i) {
        int k0 = (w + 8 * i) * 32 + kg * 8 - IDIM;      // >= 0 since kt >= 16
        wf[i * 2 + ct] = cvt8(Whh + (size_t)gr * HDIM + k0);
      }
    }
  }

  // epilogue: thread -> one cell (b = tid>>3, j = tid&7)
  const int eb = tid >> 3;
  const int ej = tid & 7;
  float bias[4];
  #pragma unroll
  for (int g = 0; g < 4; ++g) {
    int r = g * HDIM + wg * JS + ej;
    bias[g] = bih[r] + bhh[r];
  }
  float c = 0.f;

  // ---- X(0) prefetch: 2 X-tiles x 4 row-tiles = 8 frags (32 VGPRs) ----
  bf16x8 xr[8];
  #pragma unroll
  for (int ti = 0; ti < 2; ++ti)
    #pragma unroll
    for (int bt = 0; bt < 4; ++bt)
      xr[ti * 4 + bt] = *(const bf16x8*)(
        Xb + ((size_t)0 * BATCH + bt * 16 + am) * IDIM + (w + 8 * ti) * 32 + kg * 8);

  int cur = 0;
  for (int t = 0; t < T_STEPS; ++t) {
    // h A-frags: 4 h-tiles (hd = (w+8q)*32) x 4 row-tiles, chunked 8+8
    const u16* hb = hbuf + (size_t)cur * BATCH * HDIM + (size_t)am * HDIM + w * 32 + kg * 8;
    bf16x8 hA[8], hB[8];
    #pragma unroll
    for (int q = 0; q < 2; ++q)
      #pragma unroll
      for (int bt = 0; bt < 4; ++bt)
        hA[q * 4 + bt] = *(const bf16x8*)(hb + bt * 16 * HDIM + q * 256);

    f32x4 acc[2][4];
    #pragma unroll
    for (int ct = 0; ct < 2; ++ct)
      #pragma unroll
      for (int bt = 0; bt < 4; ++bt)
        acc[ct][bt] = (f32x4){0.f, 0.f, 0.f, 0.f};

    // X part from prefetched regs (covers hA latency)
    #pragma unroll
    for (int ti = 0; ti < 2; ++ti)
      #pragma unroll
      for (int bt = 0; bt < 4; ++bt) {
        MFA(0, bt, xr[ti * 4 + bt], ti);
        MFA(1, bt, xr[ti * 4 + bt], ti);
      }

    // issue hB
    #pragma unroll
    for (int q = 0; q < 2; ++q)
      #pragma unroll
      for (int bt = 0; bt < 4; ++bt)
        hB[q * 4 + bt] = *(const bf16x8*)(hb + bt * 16 * HDIM + (2 + q) * 256);

    // X(t+1) prefetch (pre-fence -> survives invalidate in regs)
    if (t != T_STEPS - 1) {
      #pragma unroll
      for (int ti = 0; ti < 2; ++ti)
        #pragma unroll
        for (int bt = 0; bt < 4; ++bt)
          xr[ti * 4 + bt] = *(const bf16x8*)(
            Xb + ((size_t)(t + 1) * BATCH + bt * 16 + am) * IDIM + (w + 8 * ti) * 32 + kg * 8);
    }

    // h MFMAs
    #pragma unroll
    for (int q = 0; q < 2; ++q)
      #pragma unroll
      for (int bt = 0; bt < 4; ++bt) {
        MFA(0, bt, hA[q * 4 + bt], 2 + q);
        MFA(1, bt, hA[q * 4 + bt], 2 + q);
      }
    #pragma unroll
    for (int q = 0; q < 2; ++q)
      #pragma unroll
      for (int bt = 0; bt < 4; ++bt) {
        MFA(0, bt, hB[q * 4 + bt], 4 + q);
        MFA(1, bt, hB[q * 4 + bt], 4 + q);
      }

    // partial sums -> LDS (f32x4 along batch dim, contiguous)
    #pragma unroll
    for (int ct = 0; ct < 2; ++ct)
      #pragma unroll
      for (int bt = 0; bt < 4; ++bt)
        *(f32x4*)&gw[w][ct * 16 + am][bt * 16 + kg * 4] = acc[ct][bt];
    __syncthreads();

    // reduce over 8 waves + activations; one cell per thread
    {
      float s0 = 0.f, s1 = 0.f, s2 = 0.f, s3 = 0.f;
      #pragma unroll
      for (int ww = 0; ww < 8; ++ww) {
        s0 += gw[ww][ej][eb];
        s1 += gw[ww][8 + ej][eb];
        s2 += gw[ww][16 + ej][eb];
        s3 += gw[ww][24 + ej][eb];
      }
      float pi = s0 + bias[0], pf = s1 + bias[1];
      float pg = s2 + bias[2], po = s3 + bias[3];
      c = sigmoidf_fast(pf) * c + sigmoidf_fast(pi) * tanhf_fast(pg);
      float h = sigmoidf_fast(po) * tanhf_fast(c);
      u16 hu = __builtin_bit_cast(u16, (bf16_t)h);
      u16* hp = hbuf + (size_t)(cur ^ 1) * BATCH * HDIM + (size_t)eb * HDIM + wg * JS + ej;
      // write-through to LLC (proven r3): no wbl2 needed at the barrier
      asm volatile("global_store_short %0, %1, off sc0 sc1"
                   :: "v"(hp), "v"((u32)hu) : "memory");
    }
    asm volatile("s_waitcnt vmcnt(0)" ::: "memory");  // own store (+X prefetch) drained
    __syncthreads();                                  // all 8 waves drained

    if (t != T_STEPS - 1) {
      if (tid < 64) {
        if (lane == 0) atomicAdd(&cnt[(wg & 7) * 32], 1u);
        u32 target = (u32)(t + 1) * (u32)NWG;
        while (true) {
          u32 v = (lane < 8)
            ? __hip_atomic_load(&cnt[lane * 32], __ATOMIC_RELAXED, __HIP_MEMORY_SCOPE_AGENT)
            : 0u;
          v += __shfl_xor(v, 1);
          v += __shfl_xor(v, 2);
          v += __shfl_xor(v, 4);
          if (__shfl(v, 0) >= target) break;
          __builtin_amdgcn_s_sleep(1);
        }
        __builtin_amdgcn_fence(__ATOMIC_ACQUIRE, "agent");  // drop stale L1/L2 h lines
      }
      __syncthreads();
    }
    cur ^= 1;
  }
}

__global__ __launch_bounds__(TPB2) void k_out(
    const u16* __restrict__ hfin, const float* __restrict__ Who,
    const float* __restrict__ bho, float* __restrict__ out) {
  int gid = blockIdx.x * TPB2 + threadIdx.x;  // 0..32767
  int b   = gid & 63;
  int oc  = gid >> 6;
  const u16* hrow = hfin + b * HDIM;
  const float* wrow = Who + oc * HDIM;
  float s = bho[oc];
  for (int k = 0; k < HDIM; k += 8) {
    bf16x8 hv = *(const bf16x8*)(hrow + k);
    f32x4 w0 = *(const f32x4*)(wrow + k);
    f32x4 w1 = *(const f32x4*)(wrow + k + 4);
    s += (float)hv[0] * w0[0] + (float)hv[1] * w0[1] + (float)hv[2] * w0[2] + (float)hv[3] * w0[3]
       + (float)hv[4] * w1[0] + (float)hv[5] * w1[1] + (float)hv[6] * w1[2] + (float)hv[7] * w1[3];
  }
  out[b * ODIM + oc] = s;
}

extern "C" void kernel_launch(void* const* d_in, const int* in_sizes, int n_in,
                              void* d_out, int out_size, void* d_ws, size_t ws_size,
                              hipStream_t stream) {
  const float* X   = (const float*)d_in[0];
  const float* Wih = (const float*)d_in[1];
  const float* Whh = (const float*)d_in[2];
  const float* bih = (const float*)d_in[3];
  const float* bhh = (const float*)d_in[4];
  const float* Who = (const float*)d_in[5];
  const float* bho = (const float*)d_in[6];

  u32* ws32 = (u32*)d_ws;
  u16* hbuf = (u16*)d_ws;
  u32* cnt  = ws32 + HBUF_U32;
  u16* Xb   = (u16*)d_ws + XB_U16_OFF;

  k_init<<<64, TPB2, 0, stream>>>(ws32);
  k_xcvt<<<(T_STEPS * BATCH * IDIM) / (TPB2 * 8), TPB2, 0, stream>>>(X, Xb);
  k_lstm<<<NWG, TPB, 0, stream>>>(Xb, Wih, Whh, bih, bhh, hbuf, cnt);
  k_out<<<(BATCH * ODIM) / TPB2, TPB2, 0, stream>>>(hbuf, Who, bho, (float*)d_out);
}